// Round 3
// baseline (620.109 us; speedup 1.0000x reference)
//
#include <hip/hip_runtime.h>
#include <cstdint>
#include <cstddef>

// Problem constants (B=2, S=4096 -> T=8192 tokens)
#define T_TOK 8192
#define DIM   1024   // D
#define NE    8      // experts
#define FF    2048   // F
#define TOPK  2

typedef __bf16 bf16x8 __attribute__((ext_vector_type(8)));
typedef float  floatx4 __attribute__((ext_vector_type(4)));

__device__ __forceinline__ unsigned short f2bf(float f) {
  unsigned int u = __float_as_uint(f);
  unsigned int r = 0x7FFFu + ((u >> 16) & 1u);   // round-to-nearest-even
  return (unsigned short)((u + r) >> 16);
}

__device__ __forceinline__ void gl_lds16(const void* g, void* l) {
  __builtin_amdgcn_global_load_lds(
      (__attribute__((address_space(1))) void*)g,
      (__attribute__((address_space(3))) void*)l,
      16, 0, 0);
}

// ---------------------------------------------------------------------------
// Transpose + f32->bf16 convert:  in[e][r][c] (f32) -> out[e][c][r] (bf16)
// ---------------------------------------------------------------------------
__global__ __launch_bounds__(256) void transpose_bf16_kernel(
    const float* __restrict__ in, unsigned short* __restrict__ out,
    int R, int C)
{
  __shared__ float tile[32][33];
  int e  = blockIdx.z;
  int c0 = blockIdx.x * 32, r0 = blockIdx.y * 32;
  int tx = threadIdx.x & 31, ty = threadIdx.x >> 5;   // 32 x 8
  const float* inp = in + (size_t)e * R * C;
  unsigned short* op = out + (size_t)e * R * C;
  for (int i = 0; i < 4; ++i)
    tile[ty + i * 8][tx] = inp[(size_t)(r0 + ty + i * 8) * C + c0 + tx];
  __syncthreads();
  for (int i = 0; i < 4; ++i)
    op[(size_t)(c0 + ty + i * 8) * R + r0 + tx] = f2bf(tile[tx][ty + i * 8]);
}

// ---------------------------------------------------------------------------
// Gating pass 1: one wave per token (4 waves/block). gw staged TRANSPOSED in
// LDS. f64 logit accumulation (top-2 robust vs np ref). Fused x->bf16.
// Block 0 also zeroes cnt[] for the parallel assign pass.
// ---------------------------------------------------------------------------
__global__ __launch_bounds__(256) void gate_kernel(
    const float* __restrict__ x, const float* __restrict__ gw,
    unsigned short* __restrict__ xb, int* __restrict__ tokExp,
    float* __restrict__ tokW, int* __restrict__ cnt)
{
  __shared__ float gwT[NE][DIM];   // 32 KB
  int tid = threadIdx.x;
  if (blockIdx.x == 0 && tid < NE) cnt[tid] = 0;
  for (int i = tid; i < DIM * NE; i += 256) {
    int d = i >> 3, e = i & 7;
    gwT[e][d] = gw[i];
  }
  __syncthreads();

  int wv = tid >> 6, lane = tid & 63;
  int t = blockIdx.x * 4 + wv;
  const float* xrow = x + (size_t)t * DIM;
  unsigned short* xbrow = xb + (size_t)t * DIM;

  double acc[NE];
  for (int e = 0; e < NE; ++e) acc[e] = 0.0;

  for (int j = 0; j < 4; ++j) {
    float4 xv = ((const float4*)xrow)[j * 64 + lane];
    ushort4 s;
    s.x = f2bf(xv.x); s.y = f2bf(xv.y); s.z = f2bf(xv.z); s.w = f2bf(xv.w);
    ((ushort4*)xbrow)[j * 64 + lane] = s;
    double xd0 = (double)xv.x, xd1 = (double)xv.y;
    double xd2 = (double)xv.z, xd3 = (double)xv.w;
    for (int e = 0; e < NE; ++e) {
      float4 g = ((const float4*)&gwT[e][0])[j * 64 + lane];
      acc[e] += xd0 * (double)g.x + xd1 * (double)g.y +
                xd2 * (double)g.z + xd3 * (double)g.w;
    }
  }

  for (int s = 32; s > 0; s >>= 1)
    for (int e = 0; e < NE; ++e)
      acc[e] += __shfl_down(acc[e], s, 64);

  if (lane == 0) {
    int e0 = 0; double v0 = acc[0];
    for (int e = 1; e < NE; ++e) if (acc[e] > v0) { v0 = acc[e]; e0 = e; }
    int e1 = -1; double v1 = -1.0e300;
    for (int e = 0; e < NE; ++e) {
      if (e == e0) continue;
      if (acc[e] > v1) { v1 = acc[e]; e1 = e; }
    }
    float a = (float)v0, b = (float)v1;
    float eb = __expf(b - a);
    float den = 1.0f + eb;
    tokExp[t] = e0 | (e1 << 8);
    tokW[2 * t + 0] = 1.0f / den;
    tokW[2 * t + 1] = eb / den;
  }
}

// ---------------------------------------------------------------------------
// Gating pass 2 (PARALLEL): 32 blocks x 256. Per-wave ballot ranks + ONE
// atomicAdd per expert per wave for the base. Slot order across waves is
// nondeterministic but output is bitwise invariant.
// ---------------------------------------------------------------------------
__global__ __launch_bounds__(256) void assign_kernel(
    const int* __restrict__ tokExp, int* __restrict__ tokEnc,
    int* __restrict__ tIdx, int* __restrict__ cnt)
{
  int t = blockIdx.x * 256 + threadIdx.x;
  int lane = threadIdx.x & 63;
  unsigned long long below = (1ull << lane) - 1ull;
  int enc = tokExp[t];
  int e0 = enc & 0xFF, e1 = (enc >> 8) & 0xFF;
  int s0 = 0, s1 = 0;
  for (int e = 0; e < NE; ++e) {
    unsigned long long m0 = __ballot(e0 == e);
    unsigned long long m1 = __ballot(e1 == e);
    int c0 = __popcll(m0), c1 = __popcll(m1);
    int base = 0;
    if (lane == 0 && (c0 + c1) > 0)
      base = atomicAdd(&cnt[e], c0 + c1);
    base = __shfl(base, 0, 64);
    if (e0 == e) s0 = base + __popcll(m0 & below);
    if (e1 == e) s1 = base + c0 + __popcll(m1 & below);
  }
  tokEnc[2 * t + 0] = (e0 << 16) | s0;
  tokEnc[2 * t + 1] = (e1 << 16) | s1;
  tIdx[e0 * T_TOK + s0] = t;
  tIdx[e1 * T_TOK + s1] = t;
}

// ---------------------------------------------------------------------------
// 256x256x(K) MFMA core, 8-phase schedule (T3+T4+T5), 512 threads / 8 waves.
// Waves: 2 (M) x 4 (N); per-wave output 128x64 = acc[8][4] 16x16 frags.
// LDS: As/Bs [2buf][8 kq][256 rows][8 elems] bf16 = 128 KB total; the
// [kq][row][8] interleave measured ZERO bank conflicts (rounds 0/2).
// Counted vmcnt(6): exactly 3 half-tiles (2 vmem insts each, per wave) stay
// in flight across every K-tile boundary; only the final tail drains to 0.
// Raw s_barrier (no counter drain) via asm with "memory" clobber; C++
// ds-reads keep compiler-managed lgkmcnt deps correct.
// Stage schedule per frame computing (t,t+1)  [derived + hand-verified]:
//   ph0: A(t+1)h0            ph4: A(t+2)h0
//   ph1: A(t+1)h1 B(t+2)h0   ph5: A(t+2)h1
//   ph2: B(t+2)h1            ph6: B(t+3)h0
//   ph3: -                   ph7: B(t+3)h1
// WAR-safe: B(t) fully consumed in its quadrant-0 phase; A(t) by ph3.
// ---------------------------------------------------------------------------
template<int KDIM>
__device__ __forceinline__ void mfma_core(
    const unsigned short* (&agp)[4], const unsigned short* (&bgp)[4],
    unsigned short* smem, floatx4 (&acc)[8][4])
{
  constexpr int NKT = KDIM / 64;    // K-tiles (16 or 32, always even)
  const int tid = threadIdx.x, lane = tid & 63, w = tid >> 6;
  const int wm = w >> 2, wn = w & 3;
  const int quad = lane >> 4, li = lane & 15;

  unsigned short (*As)[8][256][8] = (unsigned short (*)[8][256][8])smem;
  unsigned short (*Bs)[8][256][8] = (unsigned short (*)[8][256][8])(smem + 32768);

  // wave w stages k-slice kq=w; lane l writes row (half*128 + g*64 + l).
  #define STAGE_A(BUF, KT, HALF) do { \
    gl_lds16(agp[(HALF)*2+0] + (KT)*64 + w*8, &As[BUF][w][(HALF)*128 +  0][0]); \
    gl_lds16(agp[(HALF)*2+1] + (KT)*64 + w*8, &As[BUF][w][(HALF)*128 + 64][0]); } while(0)
  #define STAGE_B(BUF, KT, HALF) do { \
    gl_lds16(bgp[(HALF)*2+0] + (KT)*64 + w*8, &Bs[BUF][w][(HALF)*128 +  0][0]); \
    gl_lds16(bgp[(HALF)*2+1] + (KT)*64 + w*8, &Bs[BUF][w][(HALF)*128 + 64][0]); } while(0)

  // Prologue order matters for the vmcnt(6) invariant: B(0),A(0),B(1).
  STAGE_B(0, 0, 0); STAGE_B(0, 0, 1);
  STAGE_A(0, 0, 0); STAGE_A(0, 0, 1);
  STAGE_B(1, 1, 0); STAGE_B(1, 1, 1);

  for (int t0 = 0; t0 < NKT; t0 += 2) {
    // ---------- phases 0-3 : K-tile t0 (buf 0) ----------
    bf16x8 bf[4][2];
    #pragma unroll
    for (int q = 0; q < 4; ++q) {
      if (q == 0) STAGE_A(1, t0 + 1, 0);
      if (q == 1) { STAGE_A(1, t0 + 1, 1); if (t0 + 2 < NKT) STAGE_B(0, t0 + 2, 0); }
      if (q == 2) { if (t0 + 2 < NKT) STAGE_B(0, t0 + 2, 1); }
      if (q == 0) asm volatile("s_waitcnt vmcnt(6)" ::: "memory");
      asm volatile("s_barrier" ::: "memory");
      if (q == 0) {
        #pragma unroll
        for (int ni = 0; ni < 4; ++ni)
          #pragma unroll
          for (int kk = 0; kk < 2; ++kk)
            bf[ni][kk] = *(const bf16x8*)&Bs[0][kk * 4 + quad][wn * 64 + ni * 16 + li][0];
      }
      bf16x8 af[2][2];
      #pragma unroll
      for (int j = 0; j < 2; ++j)
        #pragma unroll
        for (int kk = 0; kk < 2; ++kk)
          af[j][kk] = *(const bf16x8*)&As[0][kk * 4 + quad][wm * 128 + (2 * q + j) * 16 + li][0];
      __builtin_amdgcn_s_setprio(1);
      #pragma unroll
      for (int j = 0; j < 2; ++j)
        #pragma unroll
        for (int ni = 0; ni < 4; ++ni)
          #pragma unroll
          for (int kk = 0; kk < 2; ++kk)
            acc[2 * q + j][ni] = __builtin_amdgcn_mfma_f32_16x16x32_bf16(
                af[j][kk], bf[ni][kk], acc[2 * q + j][ni], 0, 0, 0);
      __builtin_amdgcn_s_setprio(0);
      asm volatile("s_barrier" ::: "memory");
    }
    // ---------- phases 4-7 : K-tile t0+1 (buf 1) ----------
    #pragma unroll
    for (int q = 0; q < 4; ++q) {
      if (q == 0) { if (t0 + 2 < NKT) STAGE_A(0, t0 + 2, 0); }
      if (q == 1) { if (t0 + 2 < NKT) STAGE_A(0, t0 + 2, 1); }
      if (q == 2) { if (t0 + 3 < NKT) STAGE_B(1, t0 + 3, 0); }
      if (q == 3) { if (t0 + 3 < NKT) STAGE_B(1, t0 + 3, 1); }
      if (q == 0) {
        if (t0 + 2 < NKT) asm volatile("s_waitcnt vmcnt(6)" ::: "memory");
        else              asm volatile("s_waitcnt vmcnt(0)" ::: "memory");
      }
      asm volatile("s_barrier" ::: "memory");
      if (q == 0) {
        #pragma unroll
        for (int ni = 0; ni < 4; ++ni)
          #pragma unroll
          for (int kk = 0; kk < 2; ++kk)
            bf[ni][kk] = *(const bf16x8*)&Bs[1][kk * 4 + quad][wn * 64 + ni * 16 + li][0];
      }
      bf16x8 af[2][2];
      #pragma unroll
      for (int j = 0; j < 2; ++j)
        #pragma unroll
        for (int kk = 0; kk < 2; ++kk)
          af[j][kk] = *(const bf16x8*)&As[1][kk * 4 + quad][wm * 128 + (2 * q + j) * 16 + li][0];
      __builtin_amdgcn_s_setprio(1);
      #pragma unroll
      for (int j = 0; j < 2; ++j)
        #pragma unroll
        for (int ni = 0; ni < 4; ++ni)
          #pragma unroll
          for (int kk = 0; kk < 2; ++kk)
            acc[2 * q + j][ni] = __builtin_amdgcn_mfma_f32_16x16x32_bf16(
                af[j][kk], bf[ni][kk], acc[2 * q + j][ni], 0, 0, 0);
      __builtin_amdgcn_s_setprio(0);
      asm volatile("s_barrier" ::: "memory");
    }
  }
  #undef STAGE_A
  #undef STAGE_B
}

// ---------------------------------------------------------------------------
// GEMM1: h[row][f] = silu( sum_d xb[tok(row)][d] * w1t[e][f][d] )   (bf16 out)
// 256x256 tile, 512 threads, 8-phase core. XCD-pinned: g&7 = expert = XCD;
// within expert: m fastest -> consecutive blocks share the B panel (L2).
// ---------------------------------------------------------------------------
__global__ __launch_bounds__(512, 2) void gemm1_kernel(
    const unsigned short* __restrict__ xb,   // [T][D] bf16
    const unsigned short* __restrict__ w1t,  // [E][F][D] bf16
    unsigned short* __restrict__ h,          // [2T][F] bf16 (compacted)
    const int* __restrict__ tIdx, const int* __restrict__ cnt)
{
  int g = blockIdx.x;          // g = ((n*32 + m) << 3) | e
  int e = g & 7;
  int b = g >> 3;              // 0..255
  int m = b & 31;              // M-tile (fastest)
  int n = b >> 5;              // 0..7
  int count = cnt[e];
  int r0 = m * 256;
  if (r0 >= count) return;
  int n0 = n * 256;

  __shared__ __align__(16) unsigned short smem[2 * 8 * 256 * 8 * 2];  // 128 KB

  int tid = threadIdx.x, lane = tid & 63;
  const unsigned short* agp[4];
  const unsigned short* bgp[4];
  #pragma unroll
  for (int gq = 0; gq < 4; ++gq) {
    int r = r0 + gq * 64 + lane; if (r > count - 1) r = count - 1;
    agp[gq] = xb + (size_t)tIdx[e * T_TOK + r] * DIM;
    bgp[gq] = w1t + ((size_t)e * FF + (n0 + gq * 64 + lane)) * DIM;
  }

  floatx4 acc[8][4];
  #pragma unroll
  for (int mi = 0; mi < 8; ++mi)
    #pragma unroll
    for (int ni = 0; ni < 4; ++ni)
      #pragma unroll
      for (int qq = 0; qq < 4; ++qq) acc[mi][ni][qq] = 0.0f;

  mfma_core<DIM>(agp, bgp, smem, acc);

  size_t hb = 0;
  for (int i = 0; i < e; ++i) hb += cnt[i];
  int w = tid >> 6, wm = w >> 2, wn = w & 3, quad = lane >> 4, li = lane & 15;
  for (int mi = 0; mi < 8; ++mi) {
    int rowb = wm * 128 + mi * 16 + quad * 4;
    for (int rr = 0; rr < 4; ++rr) {
      int r = r0 + rowb + rr;
      if (r >= count) continue;
      unsigned short* hrow = h + (hb + r) * FF + n0 + wn * 64 + li;
      for (int ni = 0; ni < 4; ++ni) {
        float v = acc[mi][ni][rr];
        float s = v / (1.0f + __expf(-v));   // silu
        hrow[ni * 16] = f2bf(s);
      }
    }
  }
}

// ---------------------------------------------------------------------------
// GEMM2: yv[row][d] = sum_f h[row][f] * w2t[e][d][f]    (f32 out)
// Same 256x256 8-phase core, K = FF.
// ---------------------------------------------------------------------------
__global__ __launch_bounds__(512, 2) void gemm2_kernel(
    const unsigned short* __restrict__ h,    // [2T][F] bf16
    const unsigned short* __restrict__ w2t,  // [E][D][F] bf16
    float* __restrict__ yv,                  // [2T][D] f32
    const int* __restrict__ cnt)
{
  int g = blockIdx.x;          // g = ((n*32 + m) << 3) | e
  int e = g & 7;
  int b = g >> 3;              // 0..127
  int m = b & 31;
  int n = b >> 5;              // 0..3
  int count = cnt[e];
  int r0 = m * 256;
  if (r0 >= count) return;
  int n0 = n * 256;

  __shared__ __align__(16) unsigned short smem[2 * 8 * 256 * 8 * 2];  // 128 KB

  int tid = threadIdx.x, lane = tid & 63;
  size_t yb = 0;
  for (int i = 0; i < e; ++i) yb += cnt[i];

  const unsigned short* agp[4];
  const unsigned short* bgp[4];
  #pragma unroll
  for (int gq = 0; gq < 4; ++gq) {
    int r = r0 + gq * 64 + lane; if (r > count - 1) r = count - 1;
    agp[gq] = h + (yb + r) * FF;
    bgp[gq] = w2t + ((size_t)e * DIM + (n0 + gq * 64 + lane)) * FF;
  }

  floatx4 acc[8][4];
  #pragma unroll
  for (int mi = 0; mi < 8; ++mi)
    #pragma unroll
    for (int ni = 0; ni < 4; ++ni)
      #pragma unroll
      for (int qq = 0; qq < 4; ++qq) acc[mi][ni][qq] = 0.0f;

  mfma_core<FF>(agp, bgp, smem, acc);

  int w = tid >> 6, wm = w >> 2, wn = w & 3, quad = lane >> 4, li = lane & 15;
  for (int mi = 0; mi < 8; ++mi) {
    int rowb = wm * 128 + mi * 16 + quad * 4;
    for (int rr = 0; rr < 4; ++rr) {
      int r = r0 + rowb + rr;
      if (r >= count) continue;
      float* yrow = yv + (yb + r) * DIM + n0 + wn * 64 + li;
      for (int ni = 0; ni < 4; ++ni)
        yrow[ni * 16] = acc[mi][ni][rr];
    }
  }
}

// ---------------------------------------------------------------------------
// Combine: out[t] = w0 * yv[row0] + w1 * yv[row1]
// ---------------------------------------------------------------------------
__global__ __launch_bounds__(256) void combine_kernel(
    const float* __restrict__ yv, const int* __restrict__ tokEnc,
    const float* __restrict__ tokW, const int* __restrict__ cnt,
    float* __restrict__ out)
{
  int t = blockIdx.x;
  int i = threadIdx.x;   // 256 threads x float4 = 1024 = D
  int enc0 = tokEnc[2 * t + 0], enc1 = tokEnc[2 * t + 1];
  float w0 = tokW[2 * t + 0], w1 = tokW[2 * t + 1];
  int x0 = enc0 >> 16, x1 = enc1 >> 16;
  int off0 = 0, off1 = 0, a = 0;
  for (int e = 0; e < NE; ++e) {
    if (e == x0) off0 = a;
    if (e == x1) off1 = a;
    a += cnt[e];
  }
  size_t row0 = (size_t)off0 + (enc0 & 0xFFFF);
  size_t row1 = (size_t)off1 + (enc1 & 0xFFFF);
  float4 va = ((const float4*)(yv + row0 * DIM))[i];
  float4 vb = ((const float4*)(yv + row1 * DIM))[i];
  float4 o;
  o.x = w0 * va.x + w1 * vb.x;
  o.y = w0 * va.y + w1 * vb.y;
  o.z = w0 * va.z + w1 * vb.z;
  o.w = w0 * va.w + w1 * vb.w;
  ((float4*)(out + (size_t)t * DIM))[i] = o;
}

// ---------------------------------------------------------------------------
extern "C" void kernel_launch(void* const* d_in, const int* in_sizes, int n_in,
                              void* d_out, int out_size, void* d_ws, size_t ws_size,
                              hipStream_t stream)
{
  const float* x  = (const float*)d_in[0];   // [T][D]
  const float* gw = (const float*)d_in[1];   // [D][E]
  const float* w1 = (const float*)d_in[2];   // [E][D][F]
  const float* w2 = (const float*)d_in[3];   // [E][F][D]
  float* out = (float*)d_out;                // [T][D]

  // workspace carve-up (256B aligned)
  size_t o = 0;
  auto alloc = [&](size_t bytes) {
    void* p = (char*)d_ws + o;
    o += (bytes + 255) & ~(size_t)255;
    return p;
  };
  unsigned short* xb   = (unsigned short*)alloc((size_t)T_TOK * DIM * 2);      // 16.8 MB
  unsigned short* w1t  = (unsigned short*)alloc((size_t)NE * DIM * FF * 2);    // 33.6 MB
  unsigned short* w2t  = (unsigned short*)alloc((size_t)NE * DIM * FF * 2);    // 33.6 MB
  unsigned short* hbuf = (unsigned short*)alloc((size_t)T_TOK * TOPK * FF * 2);// 67.1 MB
  float*          yv   = (float*)alloc((size_t)T_TOK * TOPK * DIM * 4);        // 67.1 MB
  int*   tIdx   = (int*)alloc((size_t)NE * T_TOK * 4);
  int*   tokEnc = (int*)alloc((size_t)2 * T_TOK * 4);
  float* tokW   = (float*)alloc((size_t)2 * T_TOK * 4);
  int*   tokExp = (int*)alloc((size_t)T_TOK * 4);
  int*   cnt    = (int*)alloc((size_t)NE * 4);

  // w1 [E][D][F] -> w1t [E][F][D] ; w2 [E][F][D] -> w2t [E][D][F]
  transpose_bf16_kernel<<<dim3(FF / 32, DIM / 32, NE), 256, 0, stream>>>(w1, w1t, DIM, FF);
  transpose_bf16_kernel<<<dim3(DIM / 32, FF / 32, NE), 256, 0, stream>>>(w2, w2t, FF, DIM);

  gate_kernel<<<T_TOK / 4, 256, 0, stream>>>(x, gw, xb, tokExp, tokW, cnt);
  assign_kernel<<<T_TOK / 256, 256, 0, stream>>>(tokExp, tokEnc, tIdx, cnt);

  // 256^2-tile 8-phase GEMMs; grid covers worst-case count (32 M-tiles)
  gemm1_kernel<<<NE * 8 * 32, 512, 0, stream>>>(xb, w1t, hbuf, tIdx, cnt);
  gemm2_kernel<<<NE * 4 * 32, 512, 0, stream>>>(hbuf, w2t, yv, cnt);
  combine_kernel<<<T_TOK, 256, 0, stream>>>(yv, tokEnc, tokW, cnt, out);
}

// Round 4
// 544.682 us; speedup vs baseline: 1.1385x; 1.1385x over previous
//
#include <hip/hip_runtime.h>
#include <cstdint>
#include <cstddef>

// Problem constants (B=2, S=4096 -> T=8192 tokens)
#define T_TOK 8192
#define DIM   1024   // D
#define NE    8      // experts
#define FF    2048   // F
#define TOPK  2

typedef __bf16 bf16x8 __attribute__((ext_vector_type(8)));
typedef float  floatx4 __attribute__((ext_vector_type(4)));

__device__ __forceinline__ unsigned short f2bf(float f) {
  unsigned int u = __float_as_uint(f);
  unsigned int r = 0x7FFFu + ((u >> 16) & 1u);   // round-to-nearest-even
  return (unsigned short)((u + r) >> 16);
}

__device__ __forceinline__ void gl_lds16(const void* g, void* l) {
  __builtin_amdgcn_global_load_lds(
      (__attribute__((address_space(1))) void*)g,
      (__attribute__((address_space(3))) void*)l,
      16, 0, 0);
}

// ---------------------------------------------------------------------------
// Fused transpose + f32->bf16 for BOTH weights in one launch.
// z<8 : w1 [e][D][F] -> w1t [e][F][D]   (R=DIM, C=FF)
// z>=8: w2 [e][F][D] -> w2t [e][D][F]   (R=FF, C=DIM)
// Both need 2048 32x32 tiles per expert -> uniform grid (2048, 1, 16).
// ---------------------------------------------------------------------------
__global__ __launch_bounds__(256) void transpose2_bf16_kernel(
    const float* __restrict__ w1, unsigned short* __restrict__ w1t,
    const float* __restrict__ w2, unsigned short* __restrict__ w2t)
{
  __shared__ float tile[32][33];
  int z = blockIdx.z;
  int e = z & 7, sel = z >> 3;
  int R = sel ? FF : DIM;
  int C = sel ? DIM : FF;
  const float* inp = (sel ? w2 : w1) + (size_t)e * R * C;
  unsigned short* op = (sel ? w2t : w1t) + (size_t)e * R * C;
  int nc = C >> 5;                       // tiles along C
  int bx = blockIdx.x;
  int c0 = (bx % nc) * 32, r0 = (bx / nc) * 32;
  int tx = threadIdx.x & 31, ty = threadIdx.x >> 5;   // 32 x 8
  for (int i = 0; i < 4; ++i)
    tile[ty + i * 8][tx] = inp[(size_t)(r0 + ty + i * 8) * C + c0 + tx];
  __syncthreads();
  for (int i = 0; i < 4; ++i)
    op[(size_t)(c0 + ty + i * 8) * R + r0 + tx] = f2bf(tile[tx][ty + i * 8]);
}

// ---------------------------------------------------------------------------
// Gating pass 1: one wave per token (4 waves/block). gw staged TRANSPOSED in
// LDS. f64 logit accumulation (top-2 robust vs np ref). Fused x->bf16.
// Block 0 also zeroes cnt[] for the parallel assign pass.
// ---------------------------------------------------------------------------
__global__ __launch_bounds__(256) void gate_kernel(
    const float* __restrict__ x, const float* __restrict__ gw,
    unsigned short* __restrict__ xb, int* __restrict__ tokExp,
    float* __restrict__ tokW, int* __restrict__ cnt)
{
  __shared__ float gwT[NE][DIM];   // 32 KB
  int tid = threadIdx.x;
  if (blockIdx.x == 0 && tid < NE) cnt[tid] = 0;
  for (int i = tid; i < DIM * NE; i += 256) {
    int d = i >> 3, e = i & 7;
    gwT[e][d] = gw[i];
  }
  __syncthreads();

  int wv = tid >> 6, lane = tid & 63;
  int t = blockIdx.x * 4 + wv;
  const float* xrow = x + (size_t)t * DIM;
  unsigned short* xbrow = xb + (size_t)t * DIM;

  double acc[NE];
  for (int e = 0; e < NE; ++e) acc[e] = 0.0;

  for (int j = 0; j < 4; ++j) {
    float4 xv = ((const float4*)xrow)[j * 64 + lane];
    ushort4 s;
    s.x = f2bf(xv.x); s.y = f2bf(xv.y); s.z = f2bf(xv.z); s.w = f2bf(xv.w);
    ((ushort4*)xbrow)[j * 64 + lane] = s;
    double xd0 = (double)xv.x, xd1 = (double)xv.y;
    double xd2 = (double)xv.z, xd3 = (double)xv.w;
    for (int e = 0; e < NE; ++e) {
      float4 g = ((const float4*)&gwT[e][0])[j * 64 + lane];
      acc[e] += xd0 * (double)g.x + xd1 * (double)g.y +
                xd2 * (double)g.z + xd3 * (double)g.w;
    }
  }

  for (int s = 32; s > 0; s >>= 1)
    for (int e = 0; e < NE; ++e)
      acc[e] += __shfl_down(acc[e], s, 64);

  if (lane == 0) {
    int e0 = 0; double v0 = acc[0];
    for (int e = 1; e < NE; ++e) if (acc[e] > v0) { v0 = acc[e]; e0 = e; }
    int e1 = -1; double v1 = -1.0e300;
    for (int e = 0; e < NE; ++e) {
      if (e == e0) continue;
      if (acc[e] > v1) { v1 = acc[e]; e1 = e; }
    }
    float a = (float)v0, b = (float)v1;
    float eb = __expf(b - a);
    float den = 1.0f + eb;
    tokExp[t] = e0 | (e1 << 8);
    tokW[2 * t + 0] = 1.0f / den;
    tokW[2 * t + 1] = eb / den;
  }
}

// ---------------------------------------------------------------------------
// Gating pass 2 (PARALLEL): 32 blocks x 256. Per-wave ballot ranks + ONE
// atomicAdd per expert per wave for the base. Slot order across waves is
// nondeterministic but output is bitwise invariant: every output row depends
// only on its own token's row, and clamped duplicate rows never write.
// ---------------------------------------------------------------------------
__global__ __launch_bounds__(256) void assign_kernel(
    const int* __restrict__ tokExp, int* __restrict__ tokEnc,
    int* __restrict__ tIdx, int* __restrict__ cnt)
{
  int t = blockIdx.x * 256 + threadIdx.x;
  int lane = threadIdx.x & 63;
  unsigned long long below = (1ull << lane) - 1ull;
  int enc = tokExp[t];
  int e0 = enc & 0xFF, e1 = (enc >> 8) & 0xFF;
  int s0 = 0, s1 = 0;
  for (int e = 0; e < NE; ++e) {
    unsigned long long m0 = __ballot(e0 == e);
    unsigned long long m1 = __ballot(e1 == e);
    int c0 = __popcll(m0), c1 = __popcll(m1);
    int base = 0;
    if (lane == 0 && (c0 + c1) > 0)
      base = atomicAdd(&cnt[e], c0 + c1);
    base = __shfl(base, 0, 64);
    if (e0 == e) s0 = base + __popcll(m0 & below);
    if (e1 == e) s1 = base + c0 + __popcll(m1 & below);
  }
  tokEnc[2 * t + 0] = (e0 << 16) | s0;
  tokEnc[2 * t + 1] = (e1 << 16) | s1;
  tIdx[e0 * T_TOK + s0] = t;
  tIdx[e1 * T_TOK + s1] = t;
}

// ---------------------------------------------------------------------------
// GEMM1: h[row][f] = silu( sum_d xb[tok(row)][d] * w1t[e][f][d] )   (bf16 out)
// ROUND-0 PROVEN STRUCTURE: 128x128 tile, BK=64, single-buffer 2-barrier
// K-loop, 32 KB LDS, 4 blocks/CU -> cross-block overlap hides load latency.
// XCD-pinned 1-D launch: g&7 = XCD = expert; within XCD: phase(n-half) outer,
// m outer, n inner -> L2 working set = 2MB B-half + 256KB A-tile (<4MB L2).
// ---------------------------------------------------------------------------
__global__ __launch_bounds__(256, 4) void gemm1_kernel(
    const unsigned short* __restrict__ xb,   // [T][D] bf16
    const unsigned short* __restrict__ w1t,  // [E][F][D] bf16
    unsigned short* __restrict__ h,          // [2T][F] bf16 (compacted)
    const int* __restrict__ tIdx, const int* __restrict__ cnt)
{
  // decode swizzled 1-D id: g = (phase*512 + m*8 + nl)*8 + e
  int g = blockIdx.x;
  int e = g & 7;
  int b = g >> 3;              // 0..1023
  int phase = b >> 9;          // 0..1  (n-half)
  int m = (b >> 3) & 63;       // 0..63 (M-tile)
  int nl = b & 7;              // 0..7  (n within half)
  int count = cnt[e];
  int r0 = m * 128;
  if (r0 >= count) return;
  int n0 = (phase * 8 + nl) * 128;

  __shared__ __align__(16) unsigned short As[8][128][8];   // 16 KB
  __shared__ __align__(16) unsigned short Bs[8][128][8];   // 16 KB

  int tid = threadIdx.x, lane = tid & 63, w = tid >> 6;
  int wr = w >> 1, wc = w & 1;
  int quad = lane >> 4, li = lane & 15;

  const unsigned short* ag[2];
  const unsigned short* bg[2];
  for (int c = 0; c < 2; ++c) {
    int mm = c * 64 + lane;
    int r = r0 + mm; if (r > count - 1) r = count - 1;
    ag[c] = xb + (size_t)tIdx[e * T_TOK + r] * DIM;
    bg[c] = w1t + ((size_t)e * FF + (n0 + mm)) * DIM;
  }

  floatx4 acc[4][4];
  for (int mi = 0; mi < 4; ++mi)
    for (int ni = 0; ni < 4; ++ni)
      for (int q = 0; q < 4; ++q) acc[mi][ni][q] = 0.0f;

  for (int k0 = 0; k0 < DIM; k0 += 64) {
    __syncthreads();
    for (int kk = 0; kk < 2; ++kk) {
      int kq = w + kk * 4;
      gl_lds16(ag[0] + k0 + kq * 8, &As[kq][0][0]);
      gl_lds16(ag[1] + k0 + kq * 8, &As[kq][64][0]);
      gl_lds16(bg[0] + k0 + kq * 8, &Bs[kq][0][0]);
      gl_lds16(bg[1] + k0 + kq * 8, &Bs[kq][64][0]);
    }
    __syncthreads();
    for (int ks = 0; ks < 2; ++ks) {
      bf16x8 af[4], bf[4];
      for (int mi = 0; mi < 4; ++mi)
        af[mi] = *(const bf16x8*)&As[ks * 4 + quad][wr * 64 + mi * 16 + li][0];
      for (int ni = 0; ni < 4; ++ni)
        bf[ni] = *(const bf16x8*)&Bs[ks * 4 + quad][wc * 64 + ni * 16 + li][0];
      for (int mi = 0; mi < 4; ++mi)
        for (int ni = 0; ni < 4; ++ni)
          acc[mi][ni] = __builtin_amdgcn_mfma_f32_16x16x32_bf16(
              af[mi], bf[ni], acc[mi][ni], 0, 0, 0);
    }
  }

  size_t hb = 0;
  for (int i = 0; i < e; ++i) hb += cnt[i];
  for (int mi = 0; mi < 4; ++mi) {
    int rowb = wr * 64 + mi * 16 + quad * 4;
    for (int rr = 0; rr < 4; ++rr) {
      int r = r0 + rowb + rr;
      if (r >= count) continue;
      unsigned short* hrow = h + (hb + r) * FF + n0 + wc * 64 + li;
      for (int ni = 0; ni < 4; ++ni) {
        float v = acc[mi][ni][rr];
        float s = v / (1.0f + __expf(-v));   // silu
        hrow[ni * 16] = f2bf(s);
      }
    }
  }
}

// ---------------------------------------------------------------------------
// GEMM2: yv[row][d] = sum_f h[row][f] * w2t[e][d][f]    (f32 out)
// Same round-0 structure: working set = 2MB B-half + 512KB A-tile.
// ---------------------------------------------------------------------------
__global__ __launch_bounds__(256, 4) void gemm2_kernel(
    const unsigned short* __restrict__ h,    // [2T][F] bf16
    const unsigned short* __restrict__ w2t,  // [E][D][F] bf16
    float* __restrict__ yv,                  // [2T][D] f32
    const int* __restrict__ cnt)
{
  // decode swizzled 1-D id: g = (phase*256 + m*4 + nl)*8 + e
  int g = blockIdx.x;
  int e = g & 7;
  int b = g >> 3;              // 0..511
  int phase = b >> 8;          // 0..1
  int m = (b >> 2) & 63;       // 0..63
  int nl = b & 3;              // 0..3
  int count = cnt[e];
  int r0 = m * 128;
  if (r0 >= count) return;
  int n0 = (phase * 4 + nl) * 128;

  __shared__ __align__(16) unsigned short As[8][128][8];   // 16 KB
  __shared__ __align__(16) unsigned short Bs[8][128][8];   // 16 KB

  int tid = threadIdx.x, lane = tid & 63, w = tid >> 6;
  int wr = w >> 1, wc = w & 1;
  int quad = lane >> 4, li = lane & 15;
  size_t yb = 0;
  for (int i = 0; i < e; ++i) yb += cnt[i];

  const unsigned short* ag[2];
  const unsigned short* bg[2];
  for (int c = 0; c < 2; ++c) {
    int mm = c * 64 + lane;
    int r = r0 + mm; if (r > count - 1) r = count - 1;
    ag[c] = h + (yb + r) * FF;
    bg[c] = w2t + ((size_t)e * DIM + (n0 + mm)) * FF;
  }

  floatx4 acc[4][4];
  for (int mi = 0; mi < 4; ++mi)
    for (int ni = 0; ni < 4; ++ni)
      for (int q = 0; q < 4; ++q) acc[mi][ni][q] = 0.0f;

  for (int k0 = 0; k0 < FF; k0 += 64) {
    __syncthreads();
    for (int kk = 0; kk < 2; ++kk) {
      int kq = w + kk * 4;
      gl_lds16(ag[0] + k0 + kq * 8, &As[kq][0][0]);
      gl_lds16(ag[1] + k0 + kq * 8, &As[kq][64][0]);
      gl_lds16(bg[0] + k0 + kq * 8, &Bs[kq][0][0]);
      gl_lds16(bg[1] + k0 + kq * 8, &Bs[kq][64][0]);
    }
    __syncthreads();
    for (int ks = 0; ks < 2; ++ks) {
      bf16x8 af[4], bf[4];
      for (int mi = 0; mi < 4; ++mi)
        af[mi] = *(const bf16x8*)&As[ks * 4 + quad][wr * 64 + mi * 16 + li][0];
      for (int ni = 0; ni < 4; ++ni)
        bf[ni] = *(const bf16x8*)&Bs[ks * 4 + quad][wc * 64 + ni * 16 + li][0];
      for (int mi = 0; mi < 4; ++mi)
        for (int ni = 0; ni < 4; ++ni)
          acc[mi][ni] = __builtin_amdgcn_mfma_f32_16x16x32_bf16(
              af[mi], bf[ni], acc[mi][ni], 0, 0, 0);
    }
  }

  for (int mi = 0; mi < 4; ++mi) {
    int rowb = wr * 64 + mi * 16 + quad * 4;
    for (int rr = 0; rr < 4; ++rr) {
      int r = r0 + rowb + rr;
      if (r >= count) continue;
      float* yrow = yv + (yb + r) * DIM + n0 + wc * 64 + li;
      for (int ni = 0; ni < 4; ++ni)
        yrow[ni * 16] = acc[mi][ni][rr];
    }
  }
}

// ---------------------------------------------------------------------------
// Combine: out[t] = w0 * yv[row0] + w1 * yv[row1]
// off computed inline from cnt[] (branch-free select, no runtime-indexed
// local array -> no scratch).
// ---------------------------------------------------------------------------
__global__ __launch_bounds__(256) void combine_kernel(
    const float* __restrict__ yv, const int* __restrict__ tokEnc,
    const float* __restrict__ tokW, const int* __restrict__ cnt,
    float* __restrict__ out)
{
  int t = blockIdx.x;
  int i = threadIdx.x;   // 256 threads x float4 = 1024 = D
  int enc0 = tokEnc[2 * t + 0], enc1 = tokEnc[2 * t + 1];
  float w0 = tokW[2 * t + 0], w1 = tokW[2 * t + 1];
  int x0 = enc0 >> 16, x1 = enc1 >> 16;
  int off0 = 0, off1 = 0, a = 0;
  for (int e = 0; e < NE; ++e) {
    if (e == x0) off0 = a;
    if (e == x1) off1 = a;
    a += cnt[e];
  }
  size_t row0 = (size_t)off0 + (enc0 & 0xFFFF);
  size_t row1 = (size_t)off1 + (enc1 & 0xFFFF);
  float4 va = ((const float4*)(yv + row0 * DIM))[i];
  float4 vb = ((const float4*)(yv + row1 * DIM))[i];
  float4 o;
  o.x = w0 * va.x + w1 * vb.x;
  o.y = w0 * va.y + w1 * vb.y;
  o.z = w0 * va.z + w1 * vb.z;
  o.w = w0 * va.w + w1 * vb.w;
  ((float4*)(out + (size_t)t * DIM))[i] = o;
}

// ---------------------------------------------------------------------------
extern "C" void kernel_launch(void* const* d_in, const int* in_sizes, int n_in,
                              void* d_out, int out_size, void* d_ws, size_t ws_size,
                              hipStream_t stream)
{
  const float* x  = (const float*)d_in[0];   // [T][D]
  const float* gw = (const float*)d_in[1];   // [D][E]
  const float* w1 = (const float*)d_in[2];   // [E][D][F]
  const float* w2 = (const float*)d_in[3];   // [E][F][D]
  float* out = (float*)d_out;                // [T][D]

  // workspace carve-up (256B aligned)
  size_t o = 0;
  auto alloc = [&](size_t bytes) {
    void* p = (char*)d_ws + o;
    o += (bytes + 255) & ~(size_t)255;
    return p;
  };
  unsigned short* xb   = (unsigned short*)alloc((size_t)T_TOK * DIM * 2);      // 16.8 MB
  unsigned short* w1t  = (unsigned short*)alloc((size_t)NE * DIM * FF * 2);    // 33.6 MB
  unsigned short* w2t  = (unsigned short*)alloc((size_t)NE * DIM * FF * 2);    // 33.6 MB
  unsigned short* hbuf = (unsigned short*)alloc((size_t)T_TOK * TOPK * FF * 2);// 67.1 MB
  float*          yv   = (float*)alloc((size_t)T_TOK * TOPK * DIM * 4);        // 67.1 MB
  int*   tIdx   = (int*)alloc((size_t)NE * T_TOK * 4);
  int*   tokEnc = (int*)alloc((size_t)2 * T_TOK * 4);
  float* tokW   = (float*)alloc((size_t)2 * T_TOK * 4);
  int*   tokExp = (int*)alloc((size_t)T_TOK * 4);
  int*   cnt    = (int*)alloc((size_t)NE * 4);

  // both weight transposes in ONE launch (z = expert | sel<<3)
  transpose2_bf16_kernel<<<dim3(2048, 1, 2 * NE), 256, 0, stream>>>(w1, w1t, w2, w2t);

  gate_kernel<<<T_TOK / 4, 256, 0, stream>>>(x, gw, xb, tokExp, tokW, cnt);
  assign_kernel<<<T_TOK / 256, 256, 0, stream>>>(tokExp, tokEnc, tIdx, cnt);

  // XCD-pinned swizzled 1-D grids (g & 7 = XCD = expert)
  gemm1_kernel<<<8192, 256, 0, stream>>>(xb, w1t, hbuf, tIdx, cnt);
  gemm2_kernel<<<4096, 256, 0, stream>>>(hbuf, w2t, yv, cnt);
  combine_kernel<<<T_TOK, 256, 0, stream>>>(yv, tokEnc, tokW, cnt, out);
}